// Round 1
// 696.674 us; speedup vs baseline: 1.2288x; 1.2288x over previous
//
#include <hip/hip_runtime.h>

// Problem constants (from reference)
#define TOKENS  8192
#define IN_DIM  4096
#define OUT_DIM 4096
#define NUM_LUT 2
#define LUT_SIZE 16
#define VEC 8
#define GROUPS 512   // IN/VEC

typedef __bf16 bf16x8 __attribute__((ext_vector_type(8)));
typedef float  f32x4  __attribute__((ext_vector_type(4)));

__device__ __forceinline__ unsigned short f2bf(float f) {
    unsigned u = __float_as_uint(f);
    u += 0x7fffu + ((u >> 16) & 1u);   // round-to-nearest-even
    return (unsigned short)(u >> 16);
}

// ---------------------------------------------------------------------------
// Kernel 1: cast x (fp32) -> bf16, 8 elements/thread, fully vectorized
// ---------------------------------------------------------------------------
__global__ __launch_bounds__(256) void cast_x_bf16(const float* __restrict__ x,
                                                   unsigned short* __restrict__ y) {
    size_t i = ((size_t)blockIdx.x * 256 + threadIdx.x) * 8;
    float4 a = *(const float4*)(x + i);
    float4 b = *(const float4*)(x + i + 4);
    uint4 o;
    o.x = (unsigned)f2bf(a.x) | ((unsigned)f2bf(a.y) << 16);
    o.y = (unsigned)f2bf(a.z) | ((unsigned)f2bf(a.w) << 16);
    o.z = (unsigned)f2bf(b.x) | ((unsigned)f2bf(b.y) << 16);
    o.w = (unsigned)f2bf(b.z) | ((unsigned)f2bf(b.w) << 16);
    *(uint4*)(y + i) = o;
}

// ---------------------------------------------------------------------------
// Kernel 2: weight build (unchanged this round).
// ---------------------------------------------------------------------------
__global__ __launch_bounds__(256) void weight_kernel(const float* __restrict__ logits,
                                                     const float* __restrict__ luts,
                                                     unsigned short* __restrict__ W) {
    __shared__ float lsm[NUM_LUT * 16 * 132];   // [n][g_local][k*8+v], stride 132
    const int t  = threadIdx.x;
    const int g0 = blockIdx.x * 16;
    const int o0 = blockIdx.y * 16;

    {
        const int gl  = t >> 4;          // 0..15
        const int idx = (t & 15) * 8;    // 0..120
        for (int n = 0; n < NUM_LUT; ++n) {
            const float4* s = (const float4*)(luts + (size_t)n * GROUPS * LUT_SIZE * VEC
                                              + (size_t)(g0 + gl) * (LUT_SIZE * VEC) + idx);
            float4* d = (float4*)(lsm + n * (16 * 132) + gl * 132 + idx);
            d[0] = s[0];
            d[1] = s[1];
        }
    }
    __syncthreads();

    const int gl = t & 15;
    const int ol = t >> 4;
    const int o  = o0 + ol;
    const int g  = g0 + gl;

    float4 wa = make_float4(0.f, 0.f, 0.f, 0.f);
    float4 wb = make_float4(0.f, 0.f, 0.f, 0.f);

    for (int n = 0; n < NUM_LUT; ++n) {
        const float* lg = logits + (((size_t)n * OUT_DIM + o) * GROUPS + g) * LUT_SIZE;
        float v[16];
        ((float4*)v)[0] = ((const float4*)lg)[0];
        ((float4*)v)[1] = ((const float4*)lg)[1];
        ((float4*)v)[2] = ((const float4*)lg)[2];
        ((float4*)v)[3] = ((const float4*)lg)[3];

        float m = v[0];
        #pragma unroll
        for (int k = 1; k < 16; ++k) m = fmaxf(m, v[k]);
        float e[16];
        float s = 0.f;
        #pragma unroll
        for (int k = 0; k < 16; ++k) { e[k] = __expf(v[k] - m); s += e[k]; }
        const float rs = 1.0f / s;

        const float4* lut4 = (const float4*)(lsm + n * (16 * 132) + gl * 132);
        #pragma unroll
        for (int k = 0; k < 16; ++k) {
            const float sw = e[k] * rs;
            float4 a = lut4[2 * k];
            float4 b = lut4[2 * k + 1];
            wa.x += sw * a.x; wa.y += sw * a.y; wa.z += sw * a.z; wa.w += sw * a.w;
            wb.x += sw * b.x; wb.y += sw * b.y; wb.z += sw * b.z; wb.w += sw * b.w;
        }
    }

    uint4 p;
    p.x = (unsigned)f2bf(wa.x) | ((unsigned)f2bf(wa.y) << 16);
    p.y = (unsigned)f2bf(wa.z) | ((unsigned)f2bf(wa.w) << 16);
    p.z = (unsigned)f2bf(wb.x) | ((unsigned)f2bf(wb.y) << 16);
    p.w = (unsigned)f2bf(wb.z) | ((unsigned)f2bf(wb.w) << 16);
    *(uint4*)(W + (size_t)o * IN_DIM + g * VEC) = p;
}

// ---------------------------------------------------------------------------
// Kernel 3: C[M,N] = A[M,K] * B[N,K]^T + bias[N]   (bf16 in, fp32 out)
// 256x256 tile, BK=32, 8 waves (2M x 4N), phase-interleaved schedule:
//   - 4-slot LDS ring (128 KiB), prefetch 2 K-tiles ahead, counted vmcnt(4)
//     once per K-tile (never drains to 0 in the main loop)
//   - XOR-swizzled LDS (chunk c8 ^ ((row>>1)&3)) for conflict-free
//     ds_read_b128; achieved via pre-swizzled GLOBAL source addresses so
//     global_load_lds keeps its required linear destination
//   - raw s_barrier (no compiler-forced vmcnt(0) drain), setprio(1) around
//     each 16-MFMA cluster
// ---------------------------------------------------------------------------
#define BM 256
#define BN 256
#define BK 32

#define GLL(SRC, DST) __builtin_amdgcn_global_load_lds(                        \
    (const __attribute__((address_space(1))) void*)(SRC),                      \
    (__attribute__((address_space(3))) void*)(DST), 16, 0, 0)

#define STAGE_A(SBUF, KT) do {                                                 \
    GLL(Asrc + (KT),                        &lds[(SBUF) * 16384 + dOffA]);     \
    GLL(Asrc + (KT) + (size_t)128 * IN_DIM, &lds[(SBUF) * 16384 + dOffA + 4096]); \
} while (0)

#define STAGE_B(SBUF, KT) do {                                                 \
    GLL(Bsrc + (KT),                        &lds[(SBUF) * 16384 + dOffB]);     \
    GLL(Bsrc + (KT) + (size_t)128 * IN_DIM, &lds[(SBUF) * 16384 + dOffB + 4096]); \
} while (0)

#define VMCNT4 asm volatile("s_waitcnt vmcnt(4)" ::: "memory")
#define VMCNT0 asm volatile("s_waitcnt vmcnt(0)" ::: "memory")
#define BAR    __builtin_amdgcn_s_barrier()

__global__ __launch_bounds__(512, 2) void gemm_bt(const __bf16* __restrict__ A,
                                                  const __bf16* __restrict__ B,
                                                  const float* __restrict__ bias,
                                                  float* __restrict__ C) {
    // 4 ring slots x (A: 256x32 + B: 256x32) bf16 = 4 x 32 KiB = 128 KiB
    __shared__ __align__(16) __bf16 lds[4 * 16384];

    const int tid  = threadIdx.x;
    const int lane = tid & 63;
    const int wave = tid >> 6;      // 0..7
    const int wm   = wave >> 2;     // 0..1  (M half of the block tile)
    const int wn   = wave & 3;      // 0..3  (N quarter)
    const int lcol = lane & 15;
    const int quad = lane >> 4;

    const int rowBase = blockIdx.y * BM;
    const int colBase = blockIdx.x * BN;

    // --- swizzled ds_read addresses -------------------------------------
    // element (row r, chunk c8) lives at LDS chunk c8 ^ ((r>>1)&3)
    const int c8x  = quad ^ ((lcol >> 1) & 3);
    const int aoff = (wm * 128 + lcol) * 32 + c8x * 8;          // A slot base
    const int boff = 8192 + (wn * 64 + lcol) * 32 + c8x * 8;    // B slot base

    // --- staging: linear LDS dest, pre-swizzled global source -----------
    // thread tid fills LDS bytes [tid*16, +16) of each 8 KiB half:
    //   row = tid>>2 (+128 for second load), dest chunk c8' = tid&3,
    //   so source chunk c8 = c8' ^ ((row>>1)&3) = (tid&3) ^ ((tid>>3)&3)
    const int sRow = tid >> 2;                       // 0..127
    const int sC8  = (tid & 3) ^ ((tid >> 3) & 3);
    const __bf16* Asrc = A + (size_t)(rowBase + sRow) * IN_DIM + sC8 * 8;
    const __bf16* Bsrc = B + (size_t)(colBase + sRow) * IN_DIM + sC8 * 8;
    const int dOffA = tid * 8;          // elements; + buf*16384; second load +4096
    const int dOffB = 8192 + tid * 8;

    f32x4 acc[8][4] = {};
    bf16x8 af[4], bf[4];

    // prologue: stage K-tiles 0 and 1; wait for tile 0 (leave tile 1 in flight)
    STAGE_A(0, 0);
    STAGE_B(0, 0);
    STAGE_A(1, BK);
    STAGE_B(1, BK);
    VMCNT4;
    BAR;

    for (int h = 0; h < IN_DIM / BK; ++h) {
        const int buf  = h & 3;
        const int sbuf = (h + 2) & 3;
        const int ktn  = ((h + 2) & (IN_DIM / BK - 1)) * BK;  // wraps harmlessly at tail

        // ---- phase 0: M-half 0 ----
        {
            const __bf16* bp_ = &lds[buf * 16384 + boff];
            bf[0] = *(const bf16x8*)(bp_);
            bf[1] = *(const bf16x8*)(bp_ + 512);
            bf[2] = *(const bf16x8*)(bp_ + 1024);
            bf[3] = *(const bf16x8*)(bp_ + 1536);
            const __bf16* ap_ = &lds[buf * 16384 + aoff];
            af[0] = *(const bf16x8*)(ap_);
            af[1] = *(const bf16x8*)(ap_ + 512);
            af[2] = *(const bf16x8*)(ap_ + 1024);
            af[3] = *(const bf16x8*)(ap_ + 1536);
        }
        STAGE_A(sbuf, ktn);
        BAR;
        __builtin_amdgcn_s_setprio(1);
        #pragma unroll
        for (int i = 0; i < 4; ++i)
            #pragma unroll
            for (int j = 0; j < 4; ++j)
                acc[i][j] = __builtin_amdgcn_mfma_f32_16x16x32_bf16(af[i], bf[j], acc[i][j], 0, 0, 0);
        __builtin_amdgcn_s_setprio(0);
        BAR;

        // ---- phase 1: M-half 1 (reuse bf) ----
        {
            const __bf16* ap_ = &lds[buf * 16384 + aoff + 2048];
            af[0] = *(const bf16x8*)(ap_);
            af[1] = *(const bf16x8*)(ap_ + 512);
            af[2] = *(const bf16x8*)(ap_ + 1024);
            af[3] = *(const bf16x8*)(ap_ + 1536);
        }
        STAGE_B(sbuf, ktn);
        BAR;
        __builtin_amdgcn_s_setprio(1);
        #pragma unroll
        for (int i = 0; i < 4; ++i)
            #pragma unroll
            for (int j = 0; j < 4; ++j)
                acc[4 + i][j] = __builtin_amdgcn_mfma_f32_16x16x32_bf16(af[i], bf[j], acc[4 + i][j], 0, 0, 0);
        __builtin_amdgcn_s_setprio(0);
        VMCNT4;   // guarantee K-tile h+1 fully landed before next iteration reads it
        BAR;
    }

    VMCNT0;  // drain the harmless wrap-around prefetches before ending

    // epilogue: C/D layout col = lane&15, row = quad*4 + reg
    #pragma unroll
    for (int j = 0; j < 4; ++j) {
        const int col = colBase + wn * 64 + j * 16 + lcol;
        const float bv = bias[col];
        #pragma unroll
        for (int i = 0; i < 8; ++i) {
            const int row0 = rowBase + wm * 128 + i * 16 + quad * 4;
            #pragma unroll
            for (int r = 0; r < 4; ++r) {
                C[(size_t)(row0 + r) * OUT_DIM + col] = acc[i][j][r] + bv;
            }
        }
    }
}

// ---------------------------------------------------------------------------
// Launch
// ---------------------------------------------------------------------------
extern "C" void kernel_launch(void* const* d_in, const int* in_sizes, int n_in,
                              void* d_out, int out_size, void* d_ws, size_t ws_size,
                              hipStream_t stream) {
    const float* x      = (const float*)d_in[0];
    const float* logits = (const float*)d_in[1];
    const float* luts   = (const float*)d_in[2];
    const float* bias   = (const float*)d_in[3];
    float* out = (float*)d_out;

    // workspace layout: x_bf16 (64 MB) | W_bf16 (32 MB)
    unsigned short* xb = (unsigned short*)d_ws;
    unsigned short* wb = xb + (size_t)TOKENS * IN_DIM;

    cast_x_bf16<<<(TOKENS * IN_DIM) / (256 * 8), 256, 0, stream>>>(x, xb);

    weight_kernel<<<dim3(GROUPS / 16, OUT_DIM / 16), 256, 0, stream>>>(logits, luts, wb);

    gemm_bt<<<dim3(OUT_DIM / BN, TOKENS / BM), 512, 0, stream>>>(
        (const __bf16*)xb, (const __bf16*)wb, bias, out);
}

// Round 2
// 680.488 us; speedup vs baseline: 1.2581x; 1.0238x over previous
//
#include <hip/hip_runtime.h>

// Problem constants (from reference)
#define TOKENS  8192
#define IN_DIM  4096
#define OUT_DIM 4096
#define NUM_LUT 2
#define LUT_SIZE 16
#define VEC 8
#define GROUPS 512   // IN/VEC

typedef __bf16 bf16x8 __attribute__((ext_vector_type(8)));
typedef float  f32x4  __attribute__((ext_vector_type(4)));

__device__ __forceinline__ unsigned short f2bf(float f) {
    unsigned u = __float_as_uint(f);
    u += 0x7fffu + ((u >> 16) & 1u);   // round-to-nearest-even
    return (unsigned short)(u >> 16);
}

// ---------------------------------------------------------------------------
// Kernel 1 (fused): cast x -> bf16  AND  weight build, split by blockIdx.
// Fusion removes one launch gap and overlaps two independent memory streams.
// ---------------------------------------------------------------------------
#define CAST_BLOCKS ((TOKENS * IN_DIM) / (256 * 8))   // 16384

__global__ __launch_bounds__(256) void prep_kernel(const float* __restrict__ x,
                                                   unsigned short* __restrict__ xb,
                                                   const float* __restrict__ logits,
                                                   const float* __restrict__ luts,
                                                   unsigned short* __restrict__ W) {
    __shared__ float lsm[NUM_LUT * 16 * 132];   // weight branch only

    if (blockIdx.x < CAST_BLOCKS) {
        // ---- cast branch: 8 fp32 -> 8 bf16 per thread, fully vectorized ----
        size_t i = ((size_t)blockIdx.x * 256 + threadIdx.x) * 8;
        float4 a = *(const float4*)(x + i);
        float4 b = *(const float4*)(x + i + 4);
        uint4 o;
        o.x = (unsigned)f2bf(a.x) | ((unsigned)f2bf(a.y) << 16);
        o.y = (unsigned)f2bf(a.z) | ((unsigned)f2bf(a.w) << 16);
        o.z = (unsigned)f2bf(b.x) | ((unsigned)f2bf(b.y) << 16);
        o.w = (unsigned)f2bf(b.z) | ((unsigned)f2bf(b.w) << 16);
        *(uint4*)(xb + i) = o;
        return;
    }

    // ---- weight branch: W[o, g*8+v] = sum_n softmax(logits[n,o,g,:]) . luts[n,g,:,v]
    const int wbid = blockIdx.x - CAST_BLOCKS;
    const int t  = threadIdx.x;
    const int g0 = (wbid & 31) * 16;        // GROUPS/16 = 32
    const int o0 = (wbid >> 5) * 16;

    {
        const int gl  = t >> 4;          // 0..15
        const int idx = (t & 15) * 8;    // 0..120
        for (int n = 0; n < NUM_LUT; ++n) {
            const float4* s = (const float4*)(luts + (size_t)n * GROUPS * LUT_SIZE * VEC
                                              + (size_t)(g0 + gl) * (LUT_SIZE * VEC) + idx);
            float4* d = (float4*)(lsm + n * (16 * 132) + gl * 132 + idx);
            d[0] = s[0];
            d[1] = s[1];
        }
    }
    __syncthreads();

    const int gl = t & 15;
    const int ol = t >> 4;
    const int o  = o0 + ol;
    const int g  = g0 + gl;

    float4 wa = make_float4(0.f, 0.f, 0.f, 0.f);
    float4 wb = make_float4(0.f, 0.f, 0.f, 0.f);

    for (int n = 0; n < NUM_LUT; ++n) {
        const float* lg = logits + (((size_t)n * OUT_DIM + o) * GROUPS + g) * LUT_SIZE;
        float v[16];
        ((float4*)v)[0] = ((const float4*)lg)[0];
        ((float4*)v)[1] = ((const float4*)lg)[1];
        ((float4*)v)[2] = ((const float4*)lg)[2];
        ((float4*)v)[3] = ((const float4*)lg)[3];

        float m = v[0];
        #pragma unroll
        for (int k = 1; k < 16; ++k) m = fmaxf(m, v[k]);
        float e[16];
        float s = 0.f;
        #pragma unroll
        for (int k = 0; k < 16; ++k) { e[k] = __expf(v[k] - m); s += e[k]; }
        const float rs = 1.0f / s;

        const float4* lut4 = (const float4*)(lsm + n * (16 * 132) + gl * 132);
        #pragma unroll
        for (int k = 0; k < 16; ++k) {
            const float sw = e[k] * rs;
            float4 a = lut4[2 * k];
            float4 b = lut4[2 * k + 1];
            wa.x += sw * a.x; wa.y += sw * a.y; wa.z += sw * a.z; wa.w += sw * a.w;
            wb.x += sw * b.x; wb.y += sw * b.y; wb.z += sw * b.z; wb.w += sw * b.w;
        }
    }

    uint4 p;
    p.x = (unsigned)f2bf(wa.x) | ((unsigned)f2bf(wa.y) << 16);
    p.y = (unsigned)f2bf(wa.z) | ((unsigned)f2bf(wa.w) << 16);
    p.z = (unsigned)f2bf(wb.x) | ((unsigned)f2bf(wb.y) << 16);
    p.w = (unsigned)f2bf(wb.z) | ((unsigned)f2bf(wb.w) << 16);
    *(uint4*)(W + (size_t)o * IN_DIM + g * VEC) = p;
}

// ---------------------------------------------------------------------------
// Kernel 2: C[M,N] = A[M,K] * B[N,K]^T + bias[N]   (bf16 in, fp32 out)
// 256x256 tile, BK=32, 8 waves (2M x 4N).
// Round-2 restructure: register-level fragment pipelining + minimal barriers.
//   - 4-slot LDS ring (128 KiB), 2 K-tiles prefetched ahead
//   - ONE vmcnt(2)+s_barrier per K-tile (mid-iteration): guarantees slot h+1
//     landed (RAW) and separates reads of slot s from the next write of s,
//     which is always >= 2 barriers later (WAR) -- provably race-free even
//     with wave drift, since fragment lgkmcnt-waits precede each MFMA use.
//   - fragments always loaded >= 1 phase before their MFMA cluster:
//       phase0: read af_b (A half-1, slot h)   while MFMA(af_a, bfr)
//       phase1: after vmcnt(2)+BAR, MFMA(af_b, bfr), then read af_a + bfr
//               from slot h+1 (landed) for next iteration's phase0
//   - XOR-swizzled LDS (chunk ^ ((row>>1)&3)) via pre-swizzled global source;
//     measured 0 bank conflicts
//   - setprio(1) around each 16-MFMA cluster
// ---------------------------------------------------------------------------
#define BM 256
#define BN 256
#define BK 32

#define GLL(SRC, DST) __builtin_amdgcn_global_load_lds(                        \
    (const __attribute__((address_space(1))) void*)(SRC),                      \
    (__attribute__((address_space(3))) void*)(DST), 16, 0, 0)

#define STAGE_A(SBUF, KT) do {                                                 \
    GLL(Asrc + (KT),                        &lds[(SBUF) * 16384 + dOffA]);     \
    GLL(Asrc + (KT) + (size_t)128 * IN_DIM, &lds[(SBUF) * 16384 + dOffA + 4096]); \
} while (0)

#define STAGE_B(SBUF, KT) do {                                                 \
    GLL(Bsrc + (KT),                        &lds[(SBUF) * 16384 + dOffB]);     \
    GLL(Bsrc + (KT) + (size_t)128 * IN_DIM, &lds[(SBUF) * 16384 + dOffB + 4096]); \
} while (0)

#define BAR __builtin_amdgcn_s_barrier()

__global__ __launch_bounds__(512, 2) void gemm_bt(const __bf16* __restrict__ A,
                                                  const __bf16* __restrict__ B,
                                                  const float* __restrict__ bias,
                                                  float* __restrict__ C) {
    // 4 ring slots x (A: 256x32 + B: 256x32) bf16 = 4 x 32 KiB = 128 KiB
    __shared__ __align__(16) __bf16 lds[4 * 16384];

    const int tid  = threadIdx.x;
    const int lane = tid & 63;
    const int wave = tid >> 6;      // 0..7
    const int wm   = wave >> 2;     // 0..1  (M half of the block tile)
    const int wn   = wave & 3;      // 0..3  (N quarter)
    const int lcol = lane & 15;
    const int quad = lane >> 4;

    const int rowBase = blockIdx.y * BM;
    const int colBase = blockIdx.x * BN;

    // swizzled ds_read addresses: element (row r, chunk c8) lives at chunk c8 ^ ((r>>1)&3)
    const int c8x  = quad ^ ((lcol >> 1) & 3);
    const int aoff = (wm * 128 + lcol) * 32 + c8x * 8;          // A slot base
    const int boff = 8192 + (wn * 64 + lcol) * 32 + c8x * 8;    // B slot base

    // staging: linear LDS dest, pre-swizzled global source
    const int sRow = tid >> 2;                       // 0..127
    const int sC8  = (tid & 3) ^ ((tid >> 3) & 3);
    const __bf16* Asrc = A + (size_t)(rowBase + sRow) * IN_DIM + sC8 * 8;
    const __bf16* Bsrc = B + (size_t)(colBase + sRow) * IN_DIM + sC8 * 8;
    const int dOffA = tid * 8;
    const int dOffB = 8192 + tid * 8;

    f32x4 acc[8][4] = {};
    bf16x8 af_a[4], af_b[4], bfr[4];

    // prologue: stage K-tiles 0 and 1; wait for tile 0 (tile 1 stays in flight)
    STAGE_A(0, 0);
    STAGE_B(0, 0);
    STAGE_A(1, BK);
    STAGE_B(1, BK);
    asm volatile("s_waitcnt vmcnt(4)" ::: "memory");
    BAR;
    {
        const __bf16* ap_ = &lds[aoff];
        af_a[0] = *(const bf16x8*)(ap_);
        af_a[1] = *(const bf16x8*)(ap_ + 512);
        af_a[2] = *(const bf16x8*)(ap_ + 1024);
        af_a[3] = *(const bf16x8*)(ap_ + 1536);
        const __bf16* bp_ = &lds[boff];
        bfr[0] = *(const bf16x8*)(bp_);
        bfr[1] = *(const bf16x8*)(bp_ + 512);
        bfr[2] = *(const bf16x8*)(bp_ + 1024);
        bfr[3] = *(const bf16x8*)(bp_ + 1536);
    }

    for (int h = 0; h < IN_DIM / BK; ++h) {
        const int buf  = h & 3;
        const int nbuf = (h + 1) & 3;
        const int sbuf = (h + 2) & 3;
        const int ktn  = ((h + 2) & (IN_DIM / BK - 1)) * BK;  // wraps harmlessly at tail

        // ---- phase 0: MFMA M-half 0 while prefetching half-1 fragments ----
        {
            const __bf16* ap_ = &lds[buf * 16384 + aoff + 2048];
            af_b[0] = *(const bf16x8*)(ap_);
            af_b[1] = *(const bf16x8*)(ap_ + 512);
            af_b[2] = *(const bf16x8*)(ap_ + 1024);
            af_b[3] = *(const bf16x8*)(ap_ + 1536);
        }
        STAGE_A(sbuf, ktn);
        __builtin_amdgcn_s_setprio(1);
        #pragma unroll
        for (int i = 0; i < 4; ++i)
            #pragma unroll
            for (int j = 0; j < 4; ++j)
                acc[i][j] = __builtin_amdgcn_mfma_f32_16x16x32_bf16(af_a[i], bfr[j], acc[i][j], 0, 0, 0);
        __builtin_amdgcn_s_setprio(0);

        // ---- sync point: slot h+1 landed for ALL waves after this ----
        asm volatile("s_waitcnt vmcnt(2)" ::: "memory");
        BAR;

        // ---- phase 1: MFMA M-half 1, then fragment loads for next K-tile ----
        STAGE_B(sbuf, ktn);
        __builtin_amdgcn_s_setprio(1);
        #pragma unroll
        for (int i = 0; i < 4; ++i)
            #pragma unroll
            for (int j = 0; j < 4; ++j)
                acc[4 + i][j] = __builtin_amdgcn_mfma_f32_16x16x32_bf16(af_b[i], bfr[j], acc[4 + i][j], 0, 0, 0);
        __builtin_amdgcn_s_setprio(0);

        {
            const __bf16* ap_ = &lds[nbuf * 16384 + aoff];
            af_a[0] = *(const bf16x8*)(ap_);
            af_a[1] = *(const bf16x8*)(ap_ + 512);
            af_a[2] = *(const bf16x8*)(ap_ + 1024);
            af_a[3] = *(const bf16x8*)(ap_ + 1536);
            const __bf16* bp_ = &lds[nbuf * 16384 + boff];
            bfr[0] = *(const bf16x8*)(bp_);
            bfr[1] = *(const bf16x8*)(bp_ + 512);
            bfr[2] = *(const bf16x8*)(bp_ + 1024);
            bfr[3] = *(const bf16x8*)(bp_ + 1536);
        }
    }

    asm volatile("s_waitcnt vmcnt(0)" ::: "memory");  // drain wrap-around prefetches

    // epilogue: C/D layout col = lane&15, row = quad*4 + reg
    #pragma unroll
    for (int j = 0; j < 4; ++j) {
        const int col = colBase + wn * 64 + j * 16 + lcol;
        const float bv = bias[col];
        #pragma unroll
        for (int i = 0; i < 8; ++i) {
            const int row0 = rowBase + wm * 128 + i * 16 + quad * 4;
            #pragma unroll
            for (int r = 0; r < 4; ++r) {
                C[(size_t)(row0 + r) * OUT_DIM + col] = acc[i][j][r] + bv;
            }
        }
    }
}

// ---------------------------------------------------------------------------
// Launch
// ---------------------------------------------------------------------------
extern "C" void kernel_launch(void* const* d_in, const int* in_sizes, int n_in,
                              void* d_out, int out_size, void* d_ws, size_t ws_size,
                              hipStream_t stream) {
    const float* x      = (const float*)d_in[0];
    const float* logits = (const float*)d_in[1];
    const float* luts   = (const float*)d_in[2];
    const float* bias   = (const float*)d_in[3];
    float* out = (float*)d_out;

    // workspace layout: x_bf16 (64 MB) | W_bf16 (32 MB)
    unsigned short* xb = (unsigned short*)d_ws;
    unsigned short* wb = xb + (size_t)TOKENS * IN_DIM;

    prep_kernel<<<CAST_BLOCKS + (GROUPS / 16) * (OUT_DIM / 16), 256, 0, stream>>>(
        x, xb, logits, luts, wb);

    gemm_bt<<<dim3(OUT_DIM / BN, TOKENS / BM), 512, 0, stream>>>(
        (const __bf16*)xb, (const __bf16*)wb, bias, out);
}